// Round 1
// baseline (17.889 us; speedup 1.0000x reference)
//
#include <hip/hip_runtime.h>

// out[b] = sum_{n=1..N} sin((2pi/K)*(x[b]+BIAS)*n)/n * (-K/pi) + (K/2 - BIAS)
//
// Strategy: per element compute theta = (2pi/K)*(x+BIAS) once (sincosf), then
// run the Chebyshev recurrence s_{n+1} = 2cos(theta)*s_n - s_{n-1} for N=1000
// steps, accumulating s_n * (1/n). 1/n weights staged in LDS (uniform
// broadcast reads, float4). 2 elements per thread for ILP + float2 coalescing.

constexpr int   NTERMS = 1000;
constexpr float BIASF  = 0.5f;
constexpr int   BLOCK  = 256;

__global__ __launch_bounds__(BLOCK)
void sawtooth_fourier_kernel(const float* __restrict__ x,
                             const float* __restrict__ Kp,
                             float* __restrict__ out,
                             int nelem)
{
    __shared__ float inv[NTERMS];
    for (int i = threadIdx.x; i < NTERMS; i += BLOCK)
        inv[i] = 1.0f / (float)(i + 1);
    __syncthreads();

    const float K      = Kp[0];
    const float c      = 6.283185307179586f / K;        // 2*pi/K
    const float scale  = -K * 0.3183098861837907f;      // -K/pi
    const float offset = 0.5f * K - BIASF;

    const int gid  = blockIdx.x * BLOCK + threadIdx.x;
    const int base = gid * 2;
    if (base + 1 >= nelem) return;   // B = 262144 is even; no tail

    const float2 xv = *reinterpret_cast<const float2*>(x + base);

    float s0, co0, s1, co1;
    sincosf(c * (xv.x + BIASF), &s0, &co0);
    sincosf(c * (xv.y + BIASF), &s1, &co1);
    const float tc0 = 2.0f * co0;
    const float tc1 = 2.0f * co1;

    // prev = sin(0*theta) = 0, cur = sin(1*theta)
    float prev0 = 0.0f, cur0 = s0, acc0 = 0.0f;
    float prev1 = 0.0f, cur1 = s1, acc1 = 0.0f;
    float nx0, nx1;

#define STEP(wv)                                              \
    acc0 = fmaf(cur0, (wv), acc0);                            \
    nx0  = fmaf(tc0, cur0, -prev0); prev0 = cur0; cur0 = nx0; \
    acc1 = fmaf(cur1, (wv), acc1);                            \
    nx1  = fmaf(tc1, cur1, -prev1); prev1 = cur1; cur1 = nx1;

    for (int i = 0; i < NTERMS; i += 4) {
        const float4 w = *reinterpret_cast<const float4*>(&inv[i]);
        STEP(w.x)
        STEP(w.y)
        STEP(w.z)
        STEP(w.w)
    }
#undef STEP

    float2 r;
    r.x = fmaf(acc0, scale, offset);
    r.y = fmaf(acc1, scale, offset);
    *reinterpret_cast<float2*>(out + base) = r;
}

extern "C" void kernel_launch(void* const* d_in, const int* in_sizes, int n_in,
                              void* d_out, int out_size, void* d_ws, size_t ws_size,
                              hipStream_t stream)
{
    const float* x  = (const float*)d_in[0];
    const float* Kp = (const float*)d_in[1];
    float* out      = (float*)d_out;

    const int nelem   = out_size;              // B = 262144
    const int threads = (nelem + 1) / 2;       // 2 elements per thread
    const int grid    = (threads + BLOCK - 1) / BLOCK;

    sawtooth_fourier_kernel<<<grid, BLOCK, 0, stream>>>(x, Kp, out, nelem);
}

// Round 2
// 10.932 us; speedup vs baseline: 1.6364x; 1.6364x over previous
//
#include <hip/hip_runtime.h>

// out[b] = sum_{n=1..N} sin(theta*n)/n * (-K/pi) + (K/2 - BIAS),
//   theta = (2pi/K)*(x[b]+BIAS),  N = 1000, K = 10, BIAS = 0.5
//
// Closed form: sum_{n=1..inf} sin(n*theta)/n = (pi - theta)/2 for theta in (0, 2pi).
// Truncated sum = (pi-theta)/2 - Im(T),  T = sum_{n>N} z^n/n,  z = e^{i*theta}.
// Abel-summation asymptotic (2 terms, error ~1e-5 for |1-z| >= 0.31):
//   T ~= z^M/(M(1-z)) - z^(M+1)/(M(M+1)(1-z)^2),  M = N+1 = 1001.
// With w = 1/(1-z) = 0.5 + i*sz/(2-2cz), this is ~20 flops + 2 sincosf per elem.

constexpr int   NTERMS = 1000;
constexpr float BIASF  = 0.5f;
constexpr int   BLOCK  = 256;

__global__ __launch_bounds__(BLOCK)
void sawtooth_closed_kernel(const float* __restrict__ x,
                            const float* __restrict__ Kp,
                            float* __restrict__ out,
                            int nelem)
{
    const float K      = Kp[0];
    const float c      = 6.283185307179586f / K;        // 2*pi/K
    const float scale  = -K * 0.3183098861837907f;      // -K/pi
    const float offset = 0.5f * K - BIASF;
    const float M      = (float)(NTERMS + 1);           // 1001
    const float invM   = 1.0f / M;
    const float invMM1 = 1.0f / (M * (M + 1.0f));

    const int base = (blockIdx.x * BLOCK + threadIdx.x) * 4;
    if (base + 3 >= nelem) return;   // B = 262144, divisible by 4

    const float4 xv = *reinterpret_cast<const float4*>(x + base);
    float4 r;

    #pragma unroll
    for (int j = 0; j < 4; ++j) {
        const float xj = (j == 0) ? xv.x : (j == 1) ? xv.y : (j == 2) ? xv.z : xv.w;
        const float th = c * (xj + BIASF);

        float sz, cz;  sincosf(th, &sz, &cz);            // z = e^{i th}
        float sp, cp;  sincosf(M * th, &sp, &cp);        // z^M

        const float wi = sz / (2.0f - 2.0f * cz);        // w = 1/(1-z) = 0.5 + i*wi

        // A = z^M * w
        const float Ar = 0.5f * cp - sp * wi;
        const float Ai = cp * wi + 0.5f * sp;
        // zw = z * w
        const float zwr = 0.5f * cz - sz * wi;
        const float zwi = cz * wi + 0.5f * sz;

        // Im(T) = Im(A)/M - Im(A*zw)/(M(M+1))
        const float ImT = Ai * invM - (Ar * zwi + Ai * zwr) * invMM1;

        const float partial = 0.5f * (3.14159265358979f - th) - ImT;
        const float o = fmaf(partial, scale, offset);
        if (j == 0) r.x = o; else if (j == 1) r.y = o; else if (j == 2) r.z = o; else r.w = o;
    }

    *reinterpret_cast<float4*>(out + base) = r;
}

extern "C" void kernel_launch(void* const* d_in, const int* in_sizes, int n_in,
                              void* d_out, int out_size, void* d_ws, size_t ws_size,
                              hipStream_t stream)
{
    const float* x  = (const float*)d_in[0];
    const float* Kp = (const float*)d_in[1];
    float* out      = (float*)d_out;

    const int nelem   = out_size;                 // B = 262144
    const int threads = (nelem + 3) / 4;          // 4 elements per thread
    const int grid    = (threads + BLOCK - 1) / BLOCK;

    sawtooth_closed_kernel<<<grid, BLOCK, 0, stream>>>(x, Kp, out, nelem);
}

// Round 3
// 9.931 us; speedup vs baseline: 1.8013x; 1.1008x over previous
//
#include <hip/hip_runtime.h>

// out[b] = sum_{n=1..N} sin(theta*n)/n * (-K/pi) + (K/2 - BIAS),
//   theta = (2pi/K)*(x[b]+BIAS), N=1000, K=10 (runtime), BIAS=0.5
//
// Identity: sum_{n=1..inf} sin(n*theta)/n = (pi-theta)/2 for theta in (0,2pi),
// and (pi-theta)/2 * (-K/pi) + K/2 - BIAS = x  exactly. So:
//   out = x + (K/pi) * Im(T),   T = sum_{n>N} z^n/n,  z = e^{i*theta}
// Tail via 2-term Abel asymptotic (error ~1e-5 for |1-z|>=0.31):
//   T ~= z^M*w/M - z^(M+1)*w^2/(M(M+1)),  M = N+1 = 1001, w = 1/(1-z).
// All trig in REVOLUTIONS via hw v_sin_f32/v_cos_f32 (no range reduction):
//   theta_rev = (x+BIAS)/K in [0.05,0.15];  M*theta_rev reduced with fract.

constexpr int   NTERMS = 1000;
constexpr float BIASF  = 0.5f;
constexpr int   BLOCK  = 256;

__global__ __launch_bounds__(BLOCK)
void sawtooth_tail_kernel(const float* __restrict__ x,
                          const float* __restrict__ Kp,
                          float* __restrict__ out,
                          int nelem)
{
    const int gid = blockIdx.x * BLOCK + threadIdx.x;
    if (gid >= nelem) return;

    const float K      = Kp[0];
    const float invK   = __builtin_amdgcn_rcpf(K);
    const float Kopi   = K * 0.3183098861837907f;          // K/pi
    const float Mf     = (float)(NTERMS + 1);              // 1001
    const float invM   = 1.0f / Mf;
    const float invMM1 = 1.0f / (Mf * (Mf + 1.0f));

    const float xv = x[gid];
    const float t  = (xv + BIASF) * invK;                  // theta, revolutions

    const float sz = __builtin_amdgcn_sinf(t);             // sin(theta)
    const float cz = __builtin_amdgcn_cosf(t);             // cos(theta)

    float u = t * Mf;                                      // M*theta, revolutions
    u -= __builtin_floorf(u);                              // reduce to [0,1)
    const float sp = __builtin_amdgcn_sinf(u);             // sin(M*theta)
    const float cp = __builtin_amdgcn_cosf(u);             // cos(M*theta)

    // w = 1/(1-z) = 0.5 + i*wi,  wi = sin(th)/(2-2cos(th))
    const float wi = sz * __builtin_amdgcn_rcpf(2.0f - 2.0f * cz);

    // A = z^M * w ;  zw = z * w
    const float Ar  = fmaf(-sp, wi, 0.5f * cp);
    const float Ai  = fmaf( cp, wi, 0.5f * sp);
    const float zwr = fmaf(-sz, wi, 0.5f * cz);
    const float zwi = fmaf( cz, wi, 0.5f * sz);

    // Im(T) = Im(A)/M - Im(A*zw)/(M(M+1))
    const float ImT = fmaf(-(Ar * zwi + Ai * zwr), invMM1, Ai * invM);

    out[gid] = fmaf(Kopi, ImT, xv);
}

extern "C" void kernel_launch(void* const* d_in, const int* in_sizes, int n_in,
                              void* d_out, int out_size, void* d_ws, size_t ws_size,
                              hipStream_t stream)
{
    const float* x  = (const float*)d_in[0];
    const float* Kp = (const float*)d_in[1];
    float* out      = (float*)d_out;

    const int nelem = out_size;                     // B = 262144
    const int grid  = (nelem + BLOCK - 1) / BLOCK;  // 1 elem/thread: max TLP

    sawtooth_tail_kernel<<<grid, BLOCK, 0, stream>>>(x, Kp, out, nelem);
}